// Round 4
// baseline (287.561 us; speedup 1.0000x reference)
//
#include <hip/hip_runtime.h>

namespace {
constexpr int DM = 1024;
constexpr int NH = 16;
constexpr int SEQ = 2048;
constexpr int NB = 4;

typedef float f32x4 __attribute__((ext_vector_type(4)));
typedef short bf16x8 __attribute__((ext_vector_type(8)));

#define WAITCNT(s) asm volatile("s_waitcnt " s ::: "memory")
#define SCHED_BAR() __builtin_amdgcn_sched_barrier(0)

__device__ inline ushort f2bf(float x) {
  union { float f; unsigned u; } v; v.f = x;
  unsigned r = v.u + 0x7fffu + ((v.u >> 16) & 1u);
  return (ushort)(r >> 16);
}

__device__ inline unsigned cvt_pk_bf16(float lo, float hi) {
  unsigned r;
  asm("v_cvt_pk_bf16_f32 %0, %1, %2" : "=v"(r) : "v"(lo), "v"(hi));
  return r;
}

__device__ inline float fast_exp2(float x) {
  float r;
  asm("v_exp_f32 %0, %1" : "=v"(r) : "v"(x));
  return r;
}

__device__ inline bf16x8 pack8(float4 a, float4 b) {
  union { bf16x8 v; unsigned u[4]; } t;
  t.u[0] = cvt_pk_bf16(a.x, a.y); t.u[1] = cvt_pk_bf16(a.z, a.w);
  t.u[2] = cvt_pk_bf16(b.x, b.y); t.u[3] = cvt_pk_bf16(b.z, b.w);
  return t.v;
}

__device__ inline void glds16(const void* g, void* l) {
  __builtin_amdgcn_global_load_lds(
      (const __attribute__((address_space(1))) void*)g,
      (__attribute__((address_space(3))) void*)l, 16, 0, 0);
}

// ---------------------------------------------------------------------------
// W prep via LDS tile transpose.
// mode 0: W[h][d][k] -> Wt[h*64+k][d];  mode 1: W[d][c] -> Wt[c][d]
// grid (DM/64, 16), block 256
// ---------------------------------------------------------------------------
__global__ __launch_bounds__(256) void prep_w(
    const float* __restrict__ W, ushort* __restrict__ Wt, int mode)
{
  __shared__ ushort T[64][72];
  const int t = threadIdx.x;
  const int d0 = blockIdx.x * 64;
  const int colbase = blockIdx.y * 64;
  #pragma unroll
  for (int pass = 0; pass < 4; ++pass) {
    const int dl = (t >> 4) + pass * 16;
    const int k = (t & 15) * 4;
    const size_t src = (mode == 0)
        ? (size_t)colbase * 1024 + (size_t)(d0 + dl) * 64 + k
        : (size_t)(d0 + dl) * 1024 + colbase + k;
    const float4 v = *reinterpret_cast<const float4*>(W + src);
    T[k + 0][dl] = f2bf(v.x); T[k + 1][dl] = f2bf(v.y);
    T[k + 2][dl] = f2bf(v.z); T[k + 3][dl] = f2bf(v.w);
  }
  __syncthreads();
  const int k = t >> 2, dp = (t & 3) * 16;
  ushort* dst = Wt + (size_t)(colbase + k) * DM + d0 + dp;
  #pragma unroll
  for (int j = 0; j < 16; ++j) dst[j] = T[k][dp + j];
}

// ---------------------------------------------------------------------------
// repack_v: Vn[bh][s][64] -> Vp[bh][kt][hd][64] LDS-image:
//   storage[hd][c*4 + t] = V[kv = (c ^ ((hd&7)<<1)) + 16*t][hd]
// grid (32, 64), block 256
// ---------------------------------------------------------------------------
__global__ __launch_bounds__(256) void repack_v(
    const ushort* __restrict__ Vn, ushort* __restrict__ Vp)
{
  __shared__ ushort T[64][80];
  const int kt = blockIdx.x, bh = blockIdx.y;
  const int tid = threadIdx.x;
  {
    const int kv = tid >> 2, hd0 = (tid & 3) * 16;
    const ushort* src = Vn + ((size_t)bh * SEQ + kt * 64 + kv) * 64 + hd0;
    *reinterpret_cast<bf16x8*>(&T[kv][hd0]) = *reinterpret_cast<const bf16x8*>(src);
    *reinterpret_cast<bf16x8*>(&T[kv][hd0 + 8]) =
        *reinterpret_cast<const bf16x8*>(src + 8);
  }
  __syncthreads();
  const int hd = tid >> 2, g = tid & 3;
  const int sw = (hd & 7) << 1;
  ushort buf[16];
  #pragma unroll
  for (int cc = 0; cc < 4; ++cc) {
    const int cp = g * 4 + cc;
    const int j = cp ^ sw;
    #pragma unroll
    for (int t = 0; t < 4; ++t) buf[cc * 4 + t] = T[j + 16 * t][hd];
  }
  ushort* dst = Vp + ((size_t)bh * 32 + kt) * 4096 + hd * 64 + g * 16;
  *reinterpret_cast<bf16x8*>(dst) = *reinterpret_cast<const bf16x8*>(&buf[0]);
  *reinterpret_cast<bf16x8*>(dst + 8) = *reinterpret_cast<const bf16x8*>(&buf[8]);
}

// ---------------------------------------------------------------------------
// MFMA GEMM, single-barrier double-buffered pipeline.
// C[row][col] = A[row][:] . Wt[col][:] + bias[col]
// Tile 128x128, BK=64, 4 waves (2x2). ASRC 0: fp32 A reg-staged;
// ASRC 1: bf16 A via global_load_lds. OMODE 0: bf16 [bh][s][hd];
// OMODE 3: fp32 [row][1024]. QS: scale output by 0.125*log2e.
// ---------------------------------------------------------------------------
template<int ASRC, int OMODE, bool QS>
__global__ __launch_bounds__(256) void gemm128(
    const void* __restrict__ Ap, const ushort* __restrict__ Bt,
    const float* __restrict__ bias, void* __restrict__ Out)
{
  __shared__ ushort As[2][128 * 64];
  __shared__ ushort Bs[2][128 * 64];
  const int tid = threadIdx.x;
  const int l = tid & 63, l15 = l & 15, l4 = l >> 4;
  const int wid = tid >> 6, wm = wid >> 1, wn = wid & 1;
  const int row0 = blockIdx.x * 128, col0 = blockIdx.y * 128;
  f32x4 acc[4][4] = {};

  // glds source precompute (per-lane): wave rows wid*32 + i*8 + (l>>3), chunk l&7
  const int gr = (wid << 5) + (l >> 3);
  const int gc = l & 7;
  const int gsw = ((l >> 3) & 7);
  const ushort* bsrc[4];
  const ushort* asrc[4];
  int bdst[4];
  #pragma unroll
  for (int i = 0; i < 4; ++i) {
    const int r = gr + i * 8;
    bsrc[i] = Bt + (size_t)(col0 + r) * DM + ((gc ^ gsw) << 3);
    bdst[i] = (wid * 32 + i * 8) * 64;
    if (ASRC == 1)
      asrc[i] = (const ushort*)Ap + (size_t)(row0 + r) * DM + ((gc ^ gsw) << 3);
  }
  // fp32 A reg-stage coords
  const int ra = tid >> 1, cb = (tid & 1) * 4;
  const float* afp = (ASRC == 0)
      ? (const float*)Ap + (size_t)(row0 + ra) * DM + cb * 8 : nullptr;

  // ---- prologue: stage k0 = 0 into buf 0 ----
  #pragma unroll
  for (int i = 0; i < 4; ++i) glds16(bsrc[i], &Bs[0][bdst[i]]);
  if (ASRC == 1) {
    #pragma unroll
    for (int i = 0; i < 4; ++i) glds16(asrc[i], &As[0][bdst[i]]);
  } else {
    #pragma unroll
    for (int j = 0; j < 4; ++j) {
      const float4 v0 = *reinterpret_cast<const float4*>(afp + j * 8);
      const float4 v1 = *reinterpret_cast<const float4*>(afp + j * 8 + 4);
      *reinterpret_cast<bf16x8*>(&As[0][ra * 64 + (((cb + j) ^ (ra & 7)) << 3)]) =
          pack8(v0, v1);
    }
  }
  WAITCNT("vmcnt(0) lgkmcnt(0)");
  SCHED_BAR();
  __builtin_amdgcn_s_barrier();
  SCHED_BAR();

  for (int t = 0; t < 16; ++t) {
    const int p = t & 1;
    const int k1 = (t < 15) ? (t + 1) * 64 : 15 * 64;
    // issue next-tile stages into buf 1-p
    #pragma unroll
    for (int i = 0; i < 4; ++i) glds16(bsrc[i] + k1, &Bs[1 - p][bdst[i]]);
    float4 av[8];
    if (ASRC == 1) {
      #pragma unroll
      for (int i = 0; i < 4; ++i) glds16(asrc[i] + k1, &As[1 - p][bdst[i]]);
    } else {
      #pragma unroll
      for (int j = 0; j < 4; ++j) {
        av[2 * j] = *reinterpret_cast<const float4*>(afp + k1 + j * 8);
        av[2 * j + 1] = *reinterpret_cast<const float4*>(afp + k1 + j * 8 + 4);
      }
    }
    // compute from buf p
    __builtin_amdgcn_s_setprio(1);
    #pragma unroll
    for (int kc = 0; kc < 2; ++kc) {
      bf16x8 a[4], bfr[4];
      #pragma unroll
      for (int m = 0; m < 4; ++m) {
        const int rr = wm * 64 + m * 16 + l15;
        a[m] = *reinterpret_cast<const bf16x8*>(
            &As[p][rr * 64 + (((kc * 4 + l4) ^ (rr & 7)) << 3)]);
      }
      #pragma unroll
      for (int n = 0; n < 4; ++n) {
        const int cc = wn * 64 + n * 16 + l15;
        bfr[n] = *reinterpret_cast<const bf16x8*>(
            &Bs[p][cc * 64 + (((kc * 4 + l4) ^ (cc & 7)) << 3)]);
      }
      #pragma unroll
      for (int m = 0; m < 4; ++m)
        #pragma unroll
        for (int n = 0; n < 4; ++n)
          acc[m][n] = __builtin_amdgcn_mfma_f32_16x16x32_bf16(
              a[m], bfr[n], acc[m][n], 0, 0, 0);
    }
    __builtin_amdgcn_s_setprio(0);
    if (ASRC == 0) {
      #pragma unroll
      for (int j = 0; j < 4; ++j) {
        *reinterpret_cast<bf16x8*>(
            &As[1 - p][ra * 64 + (((cb + j) ^ (ra & 7)) << 3)]) =
            pack8(av[2 * j], av[2 * j + 1]);
      }
    }
    WAITCNT("vmcnt(0) lgkmcnt(0)");
    SCHED_BAR();
    __builtin_amdgcn_s_barrier();
    SCHED_BAR();
  }

  constexpr float SC = 0.125f * 1.44269504088896340736f;
  #pragma unroll
  for (int m = 0; m < 4; ++m) {
    #pragma unroll
    for (int n = 0; n < 4; ++n) {
      const int col = col0 + wn * 64 + n * 16 + l15;
      const float bz = bias[col];
      #pragma unroll
      for (int r = 0; r < 4; ++r) {
        const int row = row0 + wm * 64 + m * 16 + l4 * 4 + r;
        float v = acc[m][n][r] + bz;
        if (QS) v *= SC;
        if (OMODE == 0) {
          const size_t o =
              ((size_t)((row >> 11) * NH + (col >> 6)) * SEQ + (row & 2047)) * 64
              + (col & 63);
          ((ushort*)Out)[o] = f2bf(v);
        } else {
          ((float*)Out)[(size_t)row * DM + col] = v;
        }
      }
    }
  }
}

// ---------------------------------------------------------------------------
// Flash attention, MFMA, glds double-buffered KV + counted vmcnt.
// Q (pre-scaled by 0.125*log2e), K: bf16 [bh][s][64]; Vp: packed LDS-image.
// AO: bf16 [b][s][1024]. 512 thr = 8 waves, 16 q/wave. grid (16, NH, NB).
// ---------------------------------------------------------------------------
__global__ __launch_bounds__(512) void attn_mfma(
    const ushort* __restrict__ Q, const ushort* __restrict__ K,
    const ushort* __restrict__ Vp, ushort* __restrict__ AO)
{
  __shared__ ushort Ks[2][64 * 64];
  __shared__ ushort Vs[2][64 * 64];
  __shared__ ushort Pl[8 * 16 * 64];
  const int tid = threadIdx.x;
  const int w = tid >> 6, l = tid & 63;
  const int l15 = l & 15, l4 = l >> 4;
  const int h = blockIdx.y, b = blockIdx.z;
  const int bh = b * NH + h;
  const int qbase = blockIdx.x * 128 + w * 16;
  ushort* Pw = Pl + w * (16 * 64);
  const int swzv = (l15 & 7) << 1;

  bf16x8 qf[2];
  {
    const ushort* qp = Q + ((size_t)bh * SEQ + qbase + l15) * 64 + l4 * 8;
    qf[0] = *reinterpret_cast<const bf16x8*>(qp);
    qf[1] = *reinterpret_cast<const bf16x8*>(qp + 32);
  }

  // glds source precompute
  const int krow = (w << 3) + (l >> 3);        // tile-local K row
  const int kch = l & 7;
  const ushort* ksrc = K + ((size_t)bh * SEQ + krow) * 64 + ((kch ^ (krow & 7)) << 3);
  const ushort* vsrc = Vp + (size_t)bh * (32 * 4096) + w * 512 + (l << 3);
  const int kvdst = w * 512;                   // ushorts, wave-uniform

  f32x4 oacc[4] = {};
  float m2[4], lsum[4];
  #pragma unroll
  for (int r = 0; r < 4; ++r) { m2[r] = -1e30f; lsum[r] = 0.f; }

  // prologue: stage tiles 0 and 1
  glds16(ksrc, &Ks[0][kvdst]);
  glds16(vsrc, &Vs[0][kvdst]);
  glds16(ksrc + 4096, &Ks[1][kvdst]);
  glds16(vsrc + 4096, &Vs[1][kvdst]);

  for (int kt = 0; kt < 32; ++kt) {
    const int p = kt & 1;
    WAITCNT("vmcnt(2)");
    SCHED_BAR();
    __builtin_amdgcn_s_barrier();
    SCHED_BAR();

    // QK^T (Q pre-scaled: sacc is already in log2 domain)
    f32x4 sacc[4] = {};
    __builtin_amdgcn_s_setprio(1);
    #pragma unroll
    for (int kc = 0; kc < 2; ++kc) {
      #pragma unroll
      for (int c = 0; c < 4; ++c) {
        const int kvi = c * 16 + l15;
        const bf16x8 bf = *reinterpret_cast<const bf16x8*>(
            &Ks[p][kvi * 64 + (((kc * 4 + l4) ^ (kvi & 7)) << 3)]);
        sacc[c] = __builtin_amdgcn_mfma_f32_16x16x32_bf16(qf[kc], bf, sacc[c], 0, 0, 0);
      }
    }
    __builtin_amdgcn_s_setprio(0);

    // online softmax (log2 domain), defer-max THR=8, lazy lsum
    #pragma unroll
    for (int r = 0; r < 4; ++r) {
      const float s0 = sacc[0][r], s1 = sacc[1][r];
      const float s2 = sacc[2][r], s3 = sacc[3][r];
      const float pmax = fmaxf(fmaxf(s0, s1), fmaxf(s2, s3));
      if (!__all(pmax <= m2[r] + 8.f)) {
        float t = pmax;
        t = fmaxf(t, __shfl_xor(t, 1));
        t = fmaxf(t, __shfl_xor(t, 2));
        t = fmaxf(t, __shfl_xor(t, 4));
        t = fmaxf(t, __shfl_xor(t, 8));
        const float mn = fmaxf(m2[r], t);
        const float corr = fast_exp2(m2[r] - mn);
        m2[r] = mn;
        lsum[r] *= corr;
        #pragma unroll
        for (int c = 0; c < 4; ++c) oacc[c][r] *= corr;
      }
      const float p0 = fast_exp2(s0 - m2[r]);
      const float p1 = fast_exp2(s1 - m2[r]);
      const float p2 = fast_exp2(s2 - m2[r]);
      const float p3 = fast_exp2(s3 - m2[r]);
      lsum[r] += (p0 + p1) + (p2 + p3);
      const unsigned w0 = cvt_pk_bf16(p0, p1);
      const unsigned w1 = cvt_pk_bf16(p2, p3);
      const int q = l4 * 4 + r;
      *reinterpret_cast<uint2*>(
          &Pw[q * 64 + ((l15 ^ ((q & 7) << 1)) << 2)]) = make_uint2(w0, w1);
    }

    // PV
    __builtin_amdgcn_s_setprio(1);
    #pragma unroll
    for (int kc = 0; kc < 2; ++kc) {
      const int cbk = 2 * (kc * 4 + l4);
      const bf16x8 af = *reinterpret_cast<const bf16x8*>(
          &Pw[l15 * 64 + ((cbk ^ swzv) << 2)]);
      #pragma unroll
      for (int c = 0; c < 4; ++c) {
        const int hd = c * 16 + l15;
        const bf16x8 bf = *reinterpret_cast<const bf16x8*>(
            &Vs[p][hd * 64 + ((cbk ^ swzv) << 2)]);
        oacc[c] = __builtin_amdgcn_mfma_f32_16x16x32_bf16(af, bf, oacc[c], 0, 0, 0);
      }
    }
    __builtin_amdgcn_s_setprio(0);

    __builtin_amdgcn_s_barrier();
    SCHED_BAR();
    // stage tile kt+2 into buf p (now safe: all waves done reading it)
    const int ktn = (kt + 2 < 32) ? kt + 2 : 31;
    glds16(ksrc + (size_t)ktn * 4096, &Ks[p][kvdst]);
    glds16(vsrc + (size_t)ktn * 4096, &Vs[p][kvdst]);
  }

  #pragma unroll
  for (int r = 0; r < 4; ++r) {
    float ls = lsum[r];
    ls += __shfl_xor(ls, 1);
    ls += __shfl_xor(ls, 2);
    ls += __shfl_xor(ls, 4);
    ls += __shfl_xor(ls, 8);
    const float inv = 1.f / ls;
    const int s = qbase + l4 * 4 + r;
    #pragma unroll
    for (int c = 0; c < 4; ++c) {
      AO[((size_t)b * SEQ + s) * DM + h * 64 + c * 16 + l15] =
          f2bf(oacc[c][r] * inv);
    }
  }
}

}  // namespace

extern "C" void kernel_launch(void* const* d_in, const int* in_sizes, int n_in,
                              void* d_out, int out_size, void* d_ws, size_t ws_size,
                              hipStream_t stream) {
  const float* query = (const float*)d_in[0];
  const float* key   = (const float*)d_in[1];
  const float* value = (const float*)d_in[2];
  const float* Wq    = (const float*)d_in[3];
  const float* bq    = (const float*)d_in[4];
  const float* Wk    = (const float*)d_in[5];
  const float* bk    = (const float*)d_in[6];
  const float* Wv    = (const float*)d_in[7];
  const float* bv    = (const float*)d_in[8];
  const float* Wp    = (const float*)d_in[9];
  const float* bp    = (const float*)d_in[10];
  float* out = (float*)d_out;

  char* ws = (char*)d_ws;
  const size_t MB = 1024 * 1024;
  ushort* Wtq = (ushort*)(ws + 0 * MB);
  ushort* Wtk = (ushort*)(ws + 2 * MB);
  ushort* Wtv = (ushort*)(ws + 4 * MB);
  ushort* Wtp = (ushort*)(ws + 6 * MB);
  ushort* Qb  = (ushort*)(ws + 8 * MB);
  ushort* Kb  = (ushort*)(ws + 24 * MB);
  ushort* Vn  = (ushort*)(ws + 40 * MB);  // freed after repack_v; reused for AO
  ushort* Vp  = (ushort*)(ws + 56 * MB);
  ushort* AO  = (ushort*)(ws + 40 * MB);

  dim3 gp(16, 16);
  prep_w<<<gp, 256, 0, stream>>>(Wq, Wtq, 0);
  prep_w<<<gp, 256, 0, stream>>>(Wk, Wtk, 0);
  prep_w<<<gp, 256, 0, stream>>>(Wv, Wtv, 0);
  prep_w<<<gp, 256, 0, stream>>>(Wp, Wtp, 1);

  dim3 blk(256);
  dim3 gg(64, 8);
  gemm128<0, 0, true ><<<gg, blk, 0, stream>>>(query, Wtq, bq, Qb);
  gemm128<0, 0, false><<<gg, blk, 0, stream>>>(key,   Wtk, bk, Kb);
  gemm128<0, 0, false><<<gg, blk, 0, stream>>>(value, Wtv, bv, Vn);

  repack_v<<<dim3(32, 64), 256, 0, stream>>>(Vn, Vp);

  attn_mfma<<<dim3(SEQ / 128, NH, NB), dim3(512), 0, stream>>>(Qb, Kb, Vp, AO);

  gemm128<1, 3, false><<<gg, blk, 0, stream>>>(AO, Wtp, bp, out);
}